// Round 8
// baseline (309.023 us; speedup 1.0000x reference)
//
#include <hip/hip_runtime.h>
#include <hip/hip_fp8.h>
#include <math.h>

#define H 8
#define NBLKA 256          // #chunks for scatter pass
#define BTH 1024           // threads for scatter
#define BSH 8              // 256 nodes per bucket
#define BCAP 9216          // per-bucket slot capacity (mean 8184 + 11 sigma for E=6.4M)
#define TS 1024            // threads for fused sort+layer1
#define SCAP 25600         // LDS capacity for scatter chunk (100 KB)
#define POOLG 128          // max graphs spanned per block in pooling fast path
#define KB 4               // dst buckets per layer2 block (1024 nodes, thread-per-node)
#define SLN 8192           // src nodes per h1 slice (8192 x 8B = 64KB LDS)

// ---- fp8 e4m3 helpers via HIP type (HW cvt on gfx950) ----
__device__ __forceinline__ unsigned f2fp8(float f) {
    __hip_fp8_e4m3 q(f);
    return (unsigned)q.__x;
}
__device__ __forceinline__ float fp8f(unsigned v) {
    __hip_fp8_e4m3 q;
    q.__x = (__hip_fp8_storage_t)v;
    return (float)q;
}
#if defined(__has_builtin)
#if __has_builtin(__builtin_amdgcn_cvt_pk_f32_fp8)
#define HAVE_CVT_PK_FP8 1
#endif
#endif
typedef float v2f __attribute__((ext_vector_type(2)));
__device__ __forceinline__ void unpack8(float* f, uint2 v) {
#ifdef HAVE_CVT_PK_FP8
    v2f f01 = __builtin_amdgcn_cvt_pk_f32_fp8((int)v.x, false);
    v2f f23 = __builtin_amdgcn_cvt_pk_f32_fp8((int)v.x, true);
    v2f f45 = __builtin_amdgcn_cvt_pk_f32_fp8((int)v.y, false);
    v2f f67 = __builtin_amdgcn_cvt_pk_f32_fp8((int)v.y, true);
    f[0] = f01.x; f[1] = f01.y; f[2] = f23.x; f[3] = f23.y;
    f[4] = f45.x; f[5] = f45.y; f[6] = f67.x; f[7] = f67.y;
#else
    f[0] = fp8f(v.x & 255u);         f[1] = fp8f((v.x >> 8) & 255u);
    f[2] = fp8f((v.x >> 16) & 255u); f[3] = fp8f(v.x >> 24);
    f[4] = fp8f(v.y & 255u);         f[5] = fp8f((v.y >> 8) & 255u);
    f[6] = fp8f((v.y >> 16) & 255u); f[7] = fp8f(v.y >> 24);
#endif
}

// ====== Phase A: atomic-reservation scatter into fixed-capacity bucket regions ======
// (proven R0/R6 form, untouched)
__global__ __launch_bounds__(BTH) void scatterK(const int* __restrict__ ei, int E, int NB,
                                                int chunk, int* __restrict__ cursor,
                                                unsigned* __restrict__ packed) {
    __shared__ unsigned ss[SCAP];
    __shared__ int cnt[1024], sc[1024], base[1024], cur[1024];
    int t = threadIdx.x, blk = blockIdx.x;
    cnt[t] = 0;
    __syncthreads();
    int s = blk * chunk, e = min(E, s + chunk);
    for (int i = s + t; i < e; i += BTH)
        atomicAdd(&cnt[__builtin_nontemporal_load(ei + E + i) >> BSH], 1);
    __syncthreads();
    int c = cnt[t];
    sc[t] = c;
    __syncthreads();
    for (int off = 1; off < 1024; off <<= 1) {
        int v = (t >= off) ? sc[t - off] : 0;
        __syncthreads();
        sc[t] += v;
        __syncthreads();
    }
    cur[t] = sc[t] - c;
    base[t] = (t < NB && c > 0) ? atomicAdd(&cursor[t], c) : 0;
    __syncthreads();
    for (int i = s + t; i < e; i += BTH) {
        int src = __builtin_nontemporal_load(ei + i);
        int dst = __builtin_nontemporal_load(ei + E + i);
        int pos = atomicAdd(&cur[dst >> BSH], 1);
        ss[pos] = ((unsigned)src << 8) | (unsigned)(dst & 255);
    }
    __syncthreads();
    int wave = t >> 6, lane = t & 63;
    for (int j = wave; j < NB; j += (BTH >> 6)) {
        int n = cnt[j];
        int ls = sc[j] - n;
        int bs = base[j];
        int m = min(n, BCAP - bs);
        int gs = j * BCAP + bs;
        for (int k = lane; k < m; k += 64)
            packed[gs + k] = ss[ls + k];
    }
}

// ====== Phase B: 13-bit-key counting sort (dst-major, src-slice-minor) + layer-1 MLP ======
// Key change: key = dstlow<<5 | src>>13 (8192 counters). Within each node's segment the
// sorted srcs are slice-MONOTONIC -> layer2K can slice-stage h1 in LDS (no random gather).
// Keeps R6's proven register-carried x-gather (pk/xr) + sv value-scatter + layer-1 sum.
__global__ void sortL1K(unsigned* __restrict__ packed, const int* __restrict__ bucketCnt,
                        const float* __restrict__ x, int N,
                        const float* __restrict__ W1a, const float* __restrict__ b1a,
                        const float* __restrict__ W1b, const float* __restrict__ b1b,
                        int* __restrict__ nodeStart, uint2* __restrict__ h1) {
    __shared__ unsigned ss[BCAP];             // sorted srcs (written back for layer2K)
    __shared__ float sv[BCAP];                // x[src] aligned with ss
    __shared__ unsigned cnt[SLN];             // 13-bit key counts -> excl scan -> cursors
    __shared__ int bsum[1024];
    __shared__ int nlo[256], nhi[256];
    __shared__ float sW1a[H], sb1a[H], sW1b[H * H], sb1b[H];
    int t = threadIdx.x, b = blockIdx.x;
    for (int i = t; i < SLN; i += TS) cnt[i] = 0;
    if (t < H) { sW1a[t] = W1a[t]; sb1a[t] = b1a[t]; sb1b[t] = b1b[t]; }
    else if (t >= 64 && t < 64 + H * H) sW1b[t - 64] = W1b[t - 64];
    __syncthreads();
    int s = b * BCAP;
    int n_e = min(bucketCnt[b], BCAP);
    // pass 1: count keys + early x-gather into registers (9 slots cover BCAP)
    unsigned pk[9];
    float xr[9];
#pragma unroll
    for (int k = 0; k < 9; k++) {
        int i = t + (k << 10);
        if (i < n_e) {
            unsigned p = packed[s + i];
            pk[k] = p;
            xr[k] = x[p >> 8];                // random gather overlaps counting atomics
            atomicAdd(&cnt[((p & 255u) << 5) | (p >> 21)], 1u);
        }
    }
    __syncthreads();
    // two-level exclusive scan over 8192: thread t owns [t*8, t*8+8)
    unsigned r[8], s8 = 0;
#pragma unroll
    for (int j = 0; j < 8; j++) { r[j] = cnt[(t << 3) + j]; s8 += r[j]; }
    bsum[t] = (int)s8;
    __syncthreads();
    for (int off = 1; off < 1024; off <<= 1) {
        int v = (t >= off) ? bsum[t - off] : 0;
        __syncthreads();
        bsum[t] += v;
        __syncthreads();
    }
    unsigned run = (unsigned)bsum[t] - s8;
#pragma unroll
    for (int j = 0; j < 8; j++) { cnt[(t << 3) + j] = run; run += r[j]; }
    __syncthreads();
    if (t < 256) {
        nlo[t] = (int)cnt[t << 5];            // node segment = keys [t<<5, (t+1)<<5)
        nhi[t] = (t == 255) ? n_e : (int)cnt[(t + 1) << 5];
        nodeStart[(b << BSH) + t] = s + (int)cnt[t << 5];
    }
    __syncthreads();
    // pass 2: scatter src + carried value into (dst, src-slice) order
#pragma unroll
    for (int k = 0; k < 9; k++) {
        int i = t + (k << 10);
        if (i < n_e) {
            unsigned p = pk[k];
            unsigned pos = atomicAdd(&cnt[((p & 255u) << 5) | (p >> 21)], 1u);
            ss[pos] = p >> 8;
            sv[pos] = xr[k];
        }
    }
    __syncthreads();
    // write back sorted srcs for layer2K
    for (int i = t; i < n_e; i += TS) packed[s + i] = ss[i];
    // layer-1: 4 lanes/node; segmented sum straight from LDS values
    int node = t >> 2, q4 = t & 3;
    int gn = (b << BSH) + node;
    float xself = x[min(gn, N - 1)];
    int lo = nlo[node], hi = nhi[node];
    float sum = 0.f;
    for (int k = lo + q4; k < hi; k += 4) sum += sv[k];
    sum += __shfl_xor(sum, 1, 64);
    sum += __shfl_xor(sum, 2, 64);
    if (q4 == 0 && gn < N) {
        float z = xself + sum;
        float tv[H];
#pragma unroll
        for (int k = 0; k < H; k++) tv[k] = fmaxf(fmaf(z, sW1a[k], sb1a[k]), 0.f);
        float hv[H];
#pragma unroll
        for (int j = 0; j < H; j++) {
            float a = sb1b[j];
#pragma unroll
            for (int k = 0; k < H; k++) a += tv[k] * sW1b[k * H + j];
            hv[j] = a > 0.f ? a : (expf(a) - 1.f);   // elu
        }
        uint2 o;
        o.x = f2fp8(hv[0]) | (f2fp8(hv[1]) << 8) | (f2fp8(hv[2]) << 16) | (f2fp8(hv[3]) << 24);
        o.y = f2fp8(hv[4]) | (f2fp8(hv[5]) << 8) | (f2fp8(hv[6]) << 16) | (f2fp8(hv[7]) << 24);
        h1[gn] = o;
    }
}

// ====== Phase C: layer-2 via h1 slice-broadcast through LDS (NO random global gather) ======
// Each block = KB=4 buckets (1024 nodes, thread-per-node). Loop over 64KB h1 slices:
// stage coalesced -> each thread walks its slice-monotonic edge run reading LDS.
// Edge list read as per-thread sequential global stream (L1-friendly), h1 from LDS.
__global__ __launch_bounds__(1024) void layer2K(
        const unsigned* __restrict__ packed, const int* __restrict__ nodeStart,
        const int* __restrict__ bucketCnt, const uint2* __restrict__ h1,
        int N, int NB,
        const float* __restrict__ W2a, const float* __restrict__ b2a,
        const float* __restrict__ W2b, const float* __restrict__ b2b,
        const int* __restrict__ batch, float* __restrict__ sumsCnt) {
    __shared__ uint4 sh1q[SLN / 2];           // 64KB h1 slice (16B-aligned for uint4)
    __shared__ float pool[POOLG * 9];
    __shared__ float sW2a[H * H], sb2a[H], sW2b[H * H], sb2b[H];
    uint2* sh1 = (uint2*)sh1q;
    int t = threadIdx.x, blk = blockIdx.x;
    int bb = blk * KB + (t >> 8);             // this thread's bucket
    int node = t & 255;
    int gn = (bb << 8) + node;
    bool haveB = (bb < NB);
    int sB = bb * BCAP;
    int n_e = haveB ? min(bucketCnt[bb], BCAP) : 0;
    int lo = haveB ? nodeStart[gn] : 0;
    int hi = haveB ? ((node == 255) ? (sB + n_e) : nodeStart[gn + 1]) : 0;
    if (t < H) { sb2a[t] = b2a[t]; sb2b[t] = b2b[t]; }
    else if (t >= 64 && t < 64 + H * H) sW2a[t - 64] = W2a[t - 64];
    else if (t >= 192 && t < 192 + H * H) sW2b[t - 192] = W2b[t - 192];
    int NB256 = NB << 8;                      // h1 buffer size in entries
    int NSL = (N + SLN - 1) / SLN;            // slices covering all src < N (<=32)
    float a[H] = {0.f, 0.f, 0.f, 0.f, 0.f, 0.f, 0.f, 0.f};
    int cur = lo;
    unsigned pv = (cur < hi) ? packed[cur] : 0xFFFFFFFFu;  // sentinel slice never matches
    const uint4* h4 = (const uint4*)h1;
    for (int sl = 0; sl < NSL; sl++) {
        int g0 = sl << 13;
        for (int i = t; i < (SLN >> 1); i += 1024) {
            if ((g0 + (i << 1)) < NB256) sh1q[i] = h4[(g0 >> 1) + i];
        }
        __syncthreads();
        while ((pv >> 13) == (unsigned)sl) {  // slice-monotonic run for this node
            uint2 v = sh1[pv & (SLN - 1u)];
            float f[8];
            unpack8(f, v);
#pragma unroll
            for (int j = 0; j < 8; j++) a[j] += f[j];
            cur++;
            pv = (cur < hi) ? packed[cur] : 0xFFFFFFFFu;
        }
        __syncthreads();
    }
    bool valid = haveB && (gn < N);
    float h2[H];
    int g = 0;
    if (valid) {
        uint2 vs = h1[gn];
        float zs[H];
        unpack8(zs, vs);
        float z[H];
#pragma unroll
        for (int j = 0; j < H; j++) z[j] = zs[j] + a[j];
        float tv[H];
#pragma unroll
        for (int k = 0; k < H; k++) {
            float acc = sb2a[k];
#pragma unroll
            for (int j = 0; j < H; j++) acc += z[j] * sW2a[j * H + k];
            tv[k] = fmaxf(acc, 0.f);
        }
#pragma unroll
        for (int j = 0; j < H; j++) {
            float acc = sb2b[j];
#pragma unroll
            for (int k = 0; k < H; k++) acc += tv[k] * sW2b[k * H + j];
            h2[j] = acc;
        }
        g = batch[gn];
    }
    int base = blk * (KB << 8);
    int gfirst = batch[min(base, N - 1)];
    int glast  = batch[min(base + (KB << 8) - 1, N - 1)];
    int span = glast - gfirst + 1;
    if (span <= POOLG) {
        int span9 = span * 9;
        for (int j = t; j < span9; j += 1024) pool[j] = 0.f;
        __syncthreads();
        if (valid) {
            float* p = &pool[(g - gfirst) * 9];
#pragma unroll
            for (int j = 0; j < H; j++) atomicAdd(p + j, h2[j]);
            atomicAdd(p + 8, 1.f);
        }
        __syncthreads();
        for (int j = t; j < span9; j += 1024)
            atomicAdd(&sumsCnt[(size_t)gfirst * 9 + j], pool[j]);
    } else if (valid) {
        float* p = &sumsCnt[(size_t)g * 9];
#pragma unroll
        for (int j = 0; j < H; j++) atomicAdd(p + j, h2[j]);
        atomicAdd(p + 8, 1.f);
    }
}

__global__ void finalK(const float* __restrict__ sumsCnt, const float* __restrict__ Wfc,
                       const float* __restrict__ bfc, float* __restrict__ out, int G) {
    int g = blockIdx.x * blockDim.x + threadIdx.x;
    if (g >= G) return;
    const float* s = &sumsCnt[(size_t)g * 9];
    float c = fmaxf(s[8], 1.f);
    float dot = 0.f;
#pragma unroll
    for (int j = 0; j < H; j++) dot += s[j] * Wfc[j];
    float a = dot / c + bfc[0];
    out[g] = 1.f / (1.f + expf(-a));
}

// ============================ FALLBACK (R1 atomic path) ============================
__global__ void edge_agg1(const int* __restrict__ ei, const float* __restrict__ x,
                          float* __restrict__ agg1, int E) {
    int e = blockIdx.x * blockDim.x + threadIdx.x;
    if (e >= E) return;
    atomicAdd(&agg1[ei[E + e]], x[ei[e]]);
}
__global__ void node1F(const float* __restrict__ x, const float* __restrict__ agg1,
                       const float* __restrict__ W1a, const float* __restrict__ b1a,
                       const float* __restrict__ W1b, const float* __restrict__ b1b,
                       float* __restrict__ h1, int N) {
    int n = blockIdx.x * blockDim.x + threadIdx.x;
    if (n >= N) return;
    float z = x[n] + agg1[n];
    float tv[H];
#pragma unroll
    for (int k = 0; k < H; k++) tv[k] = fmaxf(z * W1a[k] + b1a[k], 0.f);
#pragma unroll
    for (int j = 0; j < H; j++) {
        float acc = b1b[j];
#pragma unroll
        for (int k = 0; k < H; k++) acc += tv[k] * W1b[k * H + j];
        h1[(size_t)n * H + j] = acc > 0.f ? acc : (expf(acc) - 1.f);
    }
}
__global__ void edge_agg2(const int* __restrict__ ei, const float* __restrict__ h1,
                          float* __restrict__ agg2, int E) {
    long long i = (long long)blockIdx.x * blockDim.x + threadIdx.x;
    if (i >= (long long)E * H) return;
    int e = (int)(i >> 3), k = (int)(i & 7);
    atomicAdd(&agg2[(size_t)ei[E + e] * H + k], h1[(size_t)ei[e] * H + k]);
}
__global__ void node2F(const float* __restrict__ h1, const float* __restrict__ agg2,
                       const float* __restrict__ W2a, const float* __restrict__ b2a,
                       const float* __restrict__ W2b, const float* __restrict__ b2b,
                       const int* __restrict__ batch,
                       float* __restrict__ sums, float* __restrict__ counts, int N) {
    int n = blockIdx.x * blockDim.x + threadIdx.x;
    if (n >= N) return;
    float z[H], tv[H];
#pragma unroll
    for (int j = 0; j < H; j++) z[j] = h1[(size_t)n * H + j] + agg2[(size_t)n * H + j];
#pragma unroll
    for (int k = 0; k < H; k++) {
        float a = b2a[k];
#pragma unroll
        for (int j = 0; j < H; j++) a += z[j] * W2a[j * H + k];
        tv[k] = fmaxf(a, 0.f);
    }
    int g = batch[n];
#pragma unroll
    for (int j = 0; j < H; j++) {
        float a = b2b[j];
#pragma unroll
        for (int k = 0; k < H; k++) a += tv[k] * W2b[k * H + j];
        atomicAdd(&sums[(size_t)g * H + j], a);
    }
    atomicAdd(&counts[g], 1.f);
}
__global__ void finalF(const float* __restrict__ sums, const float* __restrict__ counts,
                       const float* __restrict__ Wfc, const float* __restrict__ bfc,
                       float* __restrict__ out, int G) {
    int g = blockIdx.x * blockDim.x + threadIdx.x;
    if (g >= G) return;
    float c = fmaxf(counts[g], 1.f);
    float acc = bfc[0];
#pragma unroll
    for (int j = 0; j < H; j++) acc += (sums[(size_t)g * H + j] / c) * Wfc[j];
    out[g] = 1.f / (1.f + expf(-acc));
}

// ============================ LAUNCH ============================
extern "C" void kernel_launch(void* const* d_in, const int* in_sizes, int n_in,
                              void* d_out, int out_size, void* d_ws, size_t ws_size,
                              hipStream_t stream) {
    const float* x    = (const float*)d_in[0];
    const int*   ei   = (const int*)d_in[1];
    const int*   batch= (const int*)d_in[2];
    const float* W1a  = (const float*)d_in[3];
    const float* b1a  = (const float*)d_in[4];
    const float* W1b  = (const float*)d_in[5];
    const float* b1b  = (const float*)d_in[6];
    const float* W2a  = (const float*)d_in[7];
    const float* b2a  = (const float*)d_in[8];
    const float* W2b  = (const float*)d_in[9];
    const float* b2b  = (const float*)d_in[10];
    const float* Wfc  = (const float*)d_in[11];
    const float* bfc  = (const float*)d_in[12];

    const int N = in_sizes[0];
    const int E = in_sizes[1] / 2;
    const int G = out_size;
    const int NB = (N + 255) >> BSH;
    const int chunk = (E + NBLKA - 1) / NBLKA;
    const int B = 256;

    auto rnd4 = [](size_t v) { return (v + 3) & ~(size_t)3; };
    size_t o_cur  = 0;                                    // cursor/bucketCnt [1024] (zeroed)
    size_t o_sc   = 1024;                                 // sumsCnt [9G]           (zeroed)
    size_t zelems = o_sc + (size_t)9 * G;                 // ---- memset to here ----
    size_t o_ns   = rnd4(zelems);                         // nodeStart [NB*256+1]
    size_t o_h1   = rnd4(o_ns + ((size_t)NB << BSH) + 1); // h1 fp8 [2 words/node] (16B-aligned)
    size_t o_pk   = rnd4(o_h1 + ((size_t)NB << BSH) * 2); // packed [NB*BCAP]
    size_t total  = o_pk + (size_t)NB * BCAP;

    bool srcFits = (N <= (1 << 18));                      // also: src>>13 < 32 for 13-bit key
    bool chunkFits = (chunk <= SCAP);
    bool capOK = ((size_t)E / NB) * 10 <= (size_t)BCAP * 9;
    if (NB <= 1024 && srcFits && chunkFits && capOK && ws_size >= total * 4) {
        int*      wsi = (int*)d_ws;
        float*    wsf = (float*)d_ws;
        unsigned* wsu = (unsigned*)d_ws;
        int*      cursor    = wsi + o_cur;
        float*    sumsCnt   = wsf + o_sc;
        int*      nodeStart = wsi + o_ns;
        uint2*    h1        = (uint2*)(wsu + o_h1);
        unsigned* packed    = wsu + o_pk;

        hipMemsetAsync(d_ws, 0, zelems * 4, stream);
        scatterK<<<NBLKA, BTH, 0, stream>>>(ei, E, NB, chunk, cursor, packed);
        sortL1K<<<NB, TS, 0, stream>>>(packed, cursor, x, N, W1a, b1a, W1b, b1b,
                                       nodeStart, h1);
        int NBL = (NB + KB - 1) / KB;
        layer2K<<<NBL, 1024, 0, stream>>>(packed, nodeStart, cursor, h1, N, NB,
                                          W2a, b2a, W2b, b2b, batch, sumsCnt);
        finalK<<<(G + B - 1) / B, B, 0, stream>>>(sumsCnt, Wfc, bfc, (float*)d_out, G);
    } else {
        float* ws     = (float*)d_ws;
        float* agg1   = ws;
        float* agg2   = agg1 + (size_t)N;
        float* sums   = agg2 + (size_t)8 * N;
        float* counts = sums + (size_t)8 * G;
        float* h1     = counts + (size_t)G;
        hipMemsetAsync(ws, 0, ((size_t)9 * N + (size_t)9 * G) * sizeof(float), stream);
        edge_agg1<<<(E + B - 1) / B, B, 0, stream>>>(ei, x, agg1, E);
        node1F<<<(N + B - 1) / B, B, 0, stream>>>(x, agg1, W1a, b1a, W1b, b1b, h1, N);
        long long tot = (long long)E * H;
        edge_agg2<<<(int)((tot + B - 1) / B), B, 0, stream>>>(ei, h1, agg2, E);
        node2F<<<(N + B - 1) / B, B, 0, stream>>>(h1, agg2, W2a, b2a, W2b, b2b, batch,
                                                  sums, counts, N);
        finalF<<<(G + B - 1) / B, B, 0, stream>>>(sums, counts, Wfc, bfc, (float*)d_out, G);
    }
}

// Round 9
// 297.164 us; speedup vs baseline: 1.0399x; 1.0399x over previous
//
#include <hip/hip_runtime.h>
#include <hip/hip_fp8.h>
#include <math.h>

#define H 8
#define NBLKA 256          // #chunks for scatter pass
#define BTH 1024           // threads for scatter
#define BSH 8              // 256 nodes per bucket
#define BCAP 9216          // per-bucket slot capacity (mean 8184 + 11 sigma for E=6.4M)
#define TS 1024            // threads for fused sort+layer1
#define SCAP 25600         // LDS capacity for scatter chunk (100 KB)
#define POOLG 128          // max graphs spanned per block in pooling fast path

// ---- fp8 e4m3 helpers via HIP type (HW cvt on gfx950) ----
__device__ __forceinline__ unsigned f2fp8(float f) {
    __hip_fp8_e4m3 q(f);
    return (unsigned)q.__x;
}
__device__ __forceinline__ float fp8f(unsigned v) {
    __hip_fp8_e4m3 q;
    q.__x = (__hip_fp8_storage_t)v;
    return (float)q;
}
#if defined(__has_builtin)
#if __has_builtin(__builtin_amdgcn_cvt_pk_f32_fp8)
#define HAVE_CVT_PK_FP8 1
#endif
#endif
typedef float v2f __attribute__((ext_vector_type(2)));
// unpack 8 fp8 bytes -> 8 floats; packed HW cvt (1 instr / 2 elems) when available
__device__ __forceinline__ void unpack8(float* f, uint2 v) {
#ifdef HAVE_CVT_PK_FP8
    v2f f01 = __builtin_amdgcn_cvt_pk_f32_fp8((int)v.x, false);
    v2f f23 = __builtin_amdgcn_cvt_pk_f32_fp8((int)v.x, true);
    v2f f45 = __builtin_amdgcn_cvt_pk_f32_fp8((int)v.y, false);
    v2f f67 = __builtin_amdgcn_cvt_pk_f32_fp8((int)v.y, true);
    f[0] = f01.x; f[1] = f01.y; f[2] = f23.x; f[3] = f23.y;
    f[4] = f45.x; f[5] = f45.y; f[6] = f67.x; f[7] = f67.y;
#else
    f[0] = fp8f(v.x & 255u);         f[1] = fp8f((v.x >> 8) & 255u);
    f[2] = fp8f((v.x >> 16) & 255u); f[3] = fp8f(v.x >> 24);
    f[4] = fp8f(v.y & 255u);         f[5] = fp8f((v.y >> 8) & 255u);
    f[6] = fp8f((v.y >> 16) & 255u); f[7] = fp8f(v.y >> 24);
#endif
}
__device__ __forceinline__ void acc8(float* a, uint2 v) {
    float f[8];
    unpack8(f, v);
#pragma unroll
    for (int j = 0; j < 8; j++) a[j] += f[j];
}
// agent-scope relaxed load: cross-XCD coherent read (for the fused final reduction)
__device__ __forceinline__ float ldg_ag_f32(const float* p) {
    return __hip_atomic_load(p, __ATOMIC_RELAXED, __HIP_MEMORY_SCOPE_AGENT);
}

// ====== Phase A: atomic-reservation scatter into fixed-capacity bucket regions ======
// (proven R0/R6 form, untouched)
__global__ __launch_bounds__(BTH) void scatterK(const int* __restrict__ ei, int E, int NB,
                                                int chunk, int* __restrict__ cursor,
                                                unsigned* __restrict__ packed) {
    __shared__ unsigned ss[SCAP];
    __shared__ int cnt[1024], sc[1024], base[1024], cur[1024];
    int t = threadIdx.x, blk = blockIdx.x;
    cnt[t] = 0;
    __syncthreads();
    int s = blk * chunk, e = min(E, s + chunk);
    // pass 1: count dst buckets (NT stream)
    for (int i = s + t; i < e; i += BTH)
        atomicAdd(&cnt[__builtin_nontemporal_load(ei + E + i) >> BSH], 1);
    __syncthreads();
    int c = cnt[t];
    sc[t] = c;
    __syncthreads();
    for (int off = 1; off < 1024; off <<= 1) {
        int v = (t >= off) ? sc[t - off] : 0;
        __syncthreads();
        sc[t] += v;
        __syncthreads();
    }
    cur[t] = sc[t] - c;                       // local exclusive start
    base[t] = (t < NB && c > 0) ? atomicAdd(&cursor[t], c) : 0;
    __syncthreads();
    // pass 2: re-read ei (L3-warm), LDS bucket-sort
    for (int i = s + t; i < e; i += BTH) {
        int src = __builtin_nontemporal_load(ei + i);
        int dst = __builtin_nontemporal_load(ei + E + i);
        int pos = atomicAdd(&cur[dst >> BSH], 1);
        ss[pos] = ((unsigned)src << 8) | (unsigned)(dst & 255);
    }
    __syncthreads();
    // copy-out: wave per bucket, lane per element -> coalesced full lines
    int wave = t >> 6, lane = t & 63;
    for (int j = wave; j < NB; j += (BTH >> 6)) {
        int n = cnt[j];
        int ls = sc[j] - n;
        int bs = base[j];
        int m = min(n, BCAP - bs);            // capacity guard (never hit for random dst)
        int gs = j * BCAP + bs;
        for (int k = lane; k < m; k += 64)
            packed[gs + k] = ss[ls + k];
    }
}

// ====== Phase B fused: counting sort with pass-1 register-carried x-gather + layer-1 MLP ======
// (proven R6 form, untouched: pk/xr register carry, sv value-scatter, no launch bounds)
__global__ void sortL1K(unsigned* __restrict__ packed, const int* __restrict__ bucketCnt,
                        const float* __restrict__ x, int N,
                        const float* __restrict__ W1a, const float* __restrict__ b1a,
                        const float* __restrict__ W1b, const float* __restrict__ b1b,
                        int* __restrict__ nodeStart, uint2* __restrict__ h1) {
    __shared__ unsigned ss[BCAP];             // sorted srcs (written back for layer2K)
    __shared__ float sv[BCAP];                // x[src] aligned with ss
    __shared__ int cnt[256], sb[256], cur[256];
    __shared__ float sW1a[H], sb1a[H], sW1b[H * H], sb1b[H];
    int t = threadIdx.x, b = blockIdx.x;
    if (t < 256) cnt[t] = 0;
    else if (t < 256 + H) { int j = t - 256; sW1a[j] = W1a[j]; sb1a[j] = b1a[j]; sb1b[j] = b1b[j]; }
    else if (t < 256 + H + H * H) { int j = t - 256 - H; sW1b[j] = W1b[j]; }
    __syncthreads();
    int s = b * BCAP;
    int n_e = min(bucketCnt[b], BCAP);
    // pass 1: count exact dst + early x-gather into registers (9 slots cover BCAP)
    unsigned pk[9];
    float xr[9];
#pragma unroll
    for (int k = 0; k < 9; k++) {
        int i = t + (k << 10);
        if (i < n_e) {
            unsigned p = packed[s + i];       // cached: packed is L2-warm from scatterK
            pk[k] = p;
            xr[k] = x[p >> 8];                // issued here; consumed in pass 2
            atomicAdd(&cnt[p & 255u], 1);
        }
    }
    __syncthreads();
    if (t < 256) sb[t] = cnt[t];
    __syncthreads();
    for (int off = 1; off < 256; off <<= 1) {
        int add = (t < 256 && t >= off) ? sb[t - off] : 0;
        __syncthreads();
        if (t < 256) sb[t] += add;
        __syncthreads();
    }
    if (t < 256) {
        int excl = sb[t] - cnt[t];
        cur[t] = excl;
        nodeStart[(b << BSH) + t] = s + excl;
    }
    __syncthreads();
    // pass 2: scatter src + value from registers into exact-dst order
#pragma unroll
    for (int k = 0; k < 9; k++) {
        int i = t + (k << 10);
        if (i < n_e) {
            unsigned p = pk[k];
            int pos = atomicAdd(&cur[p & 255u], 1);
            ss[pos] = p >> 8;
            sv[pos] = xr[k];
        }
    }
    __syncthreads();
    // write back sorted srcs for layer2K
    for (int i = t; i < n_e; i += TS) packed[s + i] = ss[i];
    // layer-1: 4 lanes/node; segmented sum straight from LDS values
    int node = t >> 2, q4 = t & 3;
    int gn = (b << BSH) + node;
    float xself = x[min(gn, N - 1)];          // hoisted: overlaps LDS sum
    int lo = sb[node] - cnt[node], hi = sb[node];
    float sum = 0.f;
    for (int k = lo + q4; k < hi; k += 4) sum += sv[k];
    sum += __shfl_xor(sum, 1, 64);
    sum += __shfl_xor(sum, 2, 64);
    if (q4 == 0 && gn < N) {
        float z = xself + sum;
        float tv[H];
#pragma unroll
        for (int k = 0; k < H; k++) tv[k] = fmaxf(fmaf(z, sW1a[k], sb1a[k]), 0.f);
        float hv[H];
#pragma unroll
        for (int j = 0; j < H; j++) {
            float a = sb1b[j];
#pragma unroll
            for (int k = 0; k < H; k++) a += tv[k] * sW1b[k * H + j];
            hv[j] = a > 0.f ? a : (expf(a) - 1.f);   // elu
        }
        uint2 o;
        o.x = f2fp8(hv[0]) | (f2fp8(hv[1]) << 8) | (f2fp8(hv[2]) << 16) | (f2fp8(hv[3]) << 24);
        o.y = f2fp8(hv[4]) | (f2fp8(hv[5]) << 8) | (f2fp8(hv[6]) << 16) | (f2fp8(hv[7]) << 24);
        h1[gn] = o;
    }
}

// ====== Phase C: layer-2 (proven R6 gather) + FUSED final reduction (last block) ======
// __launch_bounds__(1024, 8): cap VGPR at 64 so 2 blocks (32 waves) stay resident
__global__ __launch_bounds__(1024, 8) void layer2K(
        const unsigned* __restrict__ packed, const int* __restrict__ nodeStart,
        const int* __restrict__ bucketCnt, const uint2* __restrict__ h1, int N,
        const float* __restrict__ W2a, const float* __restrict__ b2a,
        const float* __restrict__ W2b, const float* __restrict__ b2b,
        const int* __restrict__ batch, float* __restrict__ sumsCnt,
        const float* __restrict__ Wfc, const float* __restrict__ bfc,
        float* __restrict__ out, int G, unsigned* __restrict__ doneCnt) {
    __shared__ unsigned ss[BCAP];
    __shared__ int sNS[257];
    __shared__ float pool[POOLG * 9];
    __shared__ float sW2a[H * H], sb2a[H], sW2b[H * H], sb2b[H];
    __shared__ int sLast;
    int t = threadIdx.x, b = blockIdx.x;
    int s = b * BCAP;
    int n_e = min(bucketCnt[b], BCAP);
    // stage sorted index list (coalesced, NT: single-use stream, don't evict h1 from L2)
    for (int i = t; i < n_e; i += 1024)
        ss[i] = __builtin_nontemporal_load(packed + s + i);
    if (t < 256) sNS[t] = nodeStart[(b << BSH) + t] - s;
    if (t == 256) sNS[256] = 0;               // patched below
    if (t < H) { sb2a[t] = b2a[t]; sb2b[t] = b2b[t]; }
    else if (t >= 64 && t < 64 + H * H) sW2a[t - 64] = W2a[t - 64];
    else if (t >= 192 && t < 192 + H * H) sW2b[t - 192] = W2b[t - 192];
    __syncthreads();
    if (t == 0) sNS[256] = n_e;
    __syncthreads();
    int node = t >> 2, q4 = t & 3;
    int gn = (b << BSH) + node;
    uint2 vself = h1[gn];                     // hoisted (h1 region spans all gn); overlaps loop
    int lo = sNS[node], hi = sNS[node + 1];
    float a[H] = {0.f, 0.f, 0.f, 0.f, 0.f, 0.f, 0.f, 0.f};
    for (int k0 = lo + q4; k0 < hi; k0 += 32) {
        unsigned i0 = ss[k0];
        unsigned i1 = ss[min(k0 + 4,  hi - 1)];
        unsigned i2 = ss[min(k0 + 8,  hi - 1)];
        unsigned i3 = ss[min(k0 + 12, hi - 1)];
        unsigned i4 = ss[min(k0 + 16, hi - 1)];
        unsigned i5 = ss[min(k0 + 20, hi - 1)];
        unsigned i6 = ss[min(k0 + 24, hi - 1)];
        unsigned i7 = ss[min(k0 + 28, hi - 1)];
        uint2 v0 = h1[i0];                    // 8 independent CACHED loads -> 8 outstanding
        uint2 v1 = h1[i1];
        uint2 v2 = h1[i2];
        uint2 v3 = h1[i3];
        uint2 v4 = h1[i4];
        uint2 v5 = h1[i5];
        uint2 v6 = h1[i6];
        uint2 v7 = h1[i7];
        acc8(a, v0);
        if (k0 + 4  < hi) acc8(a, v1);
        if (k0 + 8  < hi) acc8(a, v2);
        if (k0 + 12 < hi) acc8(a, v3);
        if (k0 + 16 < hi) acc8(a, v4);
        if (k0 + 20 < hi) acc8(a, v5);
        if (k0 + 24 < hi) acc8(a, v6);
        if (k0 + 28 < hi) acc8(a, v7);
    }
#pragma unroll
    for (int j = 0; j < H; j++) {
        a[j] += __shfl_xor(a[j], 1, 64);
        a[j] += __shfl_xor(a[j], 2, 64);
    }
    bool valid = (q4 == 0) && (gn < N);
    float h2[H];
    int g = 0;
    if (valid) {
        float zs[H];
        unpack8(zs, vself);
        float z[H];
#pragma unroll
        for (int j = 0; j < H; j++) z[j] = zs[j] + a[j];
        float tv[H];
#pragma unroll
        for (int k = 0; k < H; k++) {
            float acc = sb2a[k];
#pragma unroll
            for (int j = 0; j < H; j++) acc += z[j] * sW2a[j * H + k];
            tv[k] = fmaxf(acc, 0.f);
        }
#pragma unroll
        for (int j = 0; j < H; j++) {
            float acc = sb2b[j];
#pragma unroll
            for (int k = 0; k < H; k++) acc += tv[k] * sW2b[k * H + j];
            h2[j] = acc;
        }
        g = batch[gn];
    }
    int gfirst = batch[min(b << BSH, N - 1)];
    int glast  = batch[min((b << BSH) + 255, N - 1)];
    int span = glast - gfirst + 1;
    if (span <= POOLG) {
        int span9 = span * 9;
        for (int j = t; j < span9; j += 1024) pool[j] = 0.f;
        __syncthreads();
        if (valid) {
            float* p = &pool[(g - gfirst) * 9];
#pragma unroll
            for (int j = 0; j < H; j++) atomicAdd(p + j, h2[j]);
            atomicAdd(p + 8, 1.f);
        }
        __syncthreads();
        for (int j = t; j < span9; j += 1024)
            atomicAdd(&sumsCnt[(size_t)gfirst * 9 + j], pool[j]);
    } else if (valid) {
        float* p = &sumsCnt[(size_t)g * 9];
#pragma unroll
        for (int j = 0; j < H; j++) atomicAdd(p + j, h2[j]);
        atomicAdd(p + 8, 1.f);
    }
    // ---- fused final reduction: last block to finish computes out[G] ----
    if (t == 0) {
        __threadfence();                      // drain this block's sumsCnt atomics
        unsigned prev = __hip_atomic_fetch_add(doneCnt, 1u, __ATOMIC_ACQ_REL,
                                               __HIP_MEMORY_SCOPE_AGENT);
        sLast = (prev == (unsigned)(gridDim.x - 1)) ? 1 : 0;
    }
    __syncthreads();
    if (sLast) {
        for (int gg = t; gg < G; gg += 1024) {
            const float* sp = &sumsCnt[(size_t)gg * 9];
            float v[9];
#pragma unroll
            for (int j = 0; j < 9; j++) v[j] = ldg_ag_f32(sp + j);   // cross-XCD coherent
            float c = fmaxf(v[8], 1.f);
            float dot = 0.f;
#pragma unroll
            for (int j = 0; j < H; j++) dot += v[j] * Wfc[j];
            float aa = dot / c + bfc[0];
            out[gg] = 1.f / (1.f + expf(-aa));
        }
    }
}

// ============================ FALLBACK (R1 atomic path) ============================
__global__ void edge_agg1(const int* __restrict__ ei, const float* __restrict__ x,
                          float* __restrict__ agg1, int E) {
    int e = blockIdx.x * blockDim.x + threadIdx.x;
    if (e >= E) return;
    atomicAdd(&agg1[ei[E + e]], x[ei[e]]);
}
__global__ void node1F(const float* __restrict__ x, const float* __restrict__ agg1,
                       const float* __restrict__ W1a, const float* __restrict__ b1a,
                       const float* __restrict__ W1b, const float* __restrict__ b1b,
                       float* __restrict__ h1, int N) {
    int n = blockIdx.x * blockDim.x + threadIdx.x;
    if (n >= N) return;
    float z = x[n] + agg1[n];
    float tv[H];
#pragma unroll
    for (int k = 0; k < H; k++) tv[k] = fmaxf(z * W1a[k] + b1a[k], 0.f);
#pragma unroll
    for (int j = 0; j < H; j++) {
        float acc = b1b[j];
#pragma unroll
        for (int k = 0; k < H; k++) acc += tv[k] * W1b[k * H + j];
        h1[(size_t)n * H + j] = acc > 0.f ? acc : (expf(acc) - 1.f);
    }
}
__global__ void edge_agg2(const int* __restrict__ ei, const float* __restrict__ h1,
                          float* __restrict__ agg2, int E) {
    long long i = (long long)blockIdx.x * blockDim.x + threadIdx.x;
    if (i >= (long long)E * H) return;
    int e = (int)(i >> 3), k = (int)(i & 7);
    atomicAdd(&agg2[(size_t)ei[E + e] * H + k], h1[(size_t)ei[e] * H + k]);
}
__global__ void node2F(const float* __restrict__ h1, const float* __restrict__ agg2,
                       const float* __restrict__ W2a, const float* __restrict__ b2a,
                       const float* __restrict__ W2b, const float* __restrict__ b2b,
                       const int* __restrict__ batch,
                       float* __restrict__ sums, float* __restrict__ counts, int N) {
    int n = blockIdx.x * blockDim.x + threadIdx.x;
    if (n >= N) return;
    float z[H], tv[H];
#pragma unroll
    for (int j = 0; j < H; j++) z[j] = h1[(size_t)n * H + j] + agg2[(size_t)n * H + j];
#pragma unroll
    for (int k = 0; k < H; k++) {
        float a = b2a[k];
#pragma unroll
        for (int j = 0; j < H; j++) a += z[j] * W2a[j * H + k];
        tv[k] = fmaxf(a, 0.f);
    }
    int g = batch[n];
#pragma unroll
    for (int j = 0; j < H; j++) {
        float a = b2b[j];
#pragma unroll
        for (int k = 0; k < H; k++) a += tv[k] * W2b[k * H + j];
        atomicAdd(&sums[(size_t)g * H + j], a);
    }
    atomicAdd(&counts[g], 1.f);
}
__global__ void finalF(const float* __restrict__ sums, const float* __restrict__ counts,
                       const float* __restrict__ Wfc, const float* __restrict__ bfc,
                       float* __restrict__ out, int G) {
    int g = blockIdx.x * blockDim.x + threadIdx.x;
    if (g >= G) return;
    float c = fmaxf(counts[g], 1.f);
    float acc = bfc[0];
#pragma unroll
    for (int j = 0; j < H; j++) acc += (sums[(size_t)g * H + j] / c) * Wfc[j];
    out[g] = 1.f / (1.f + expf(-acc));
}

// ============================ LAUNCH ============================
extern "C" void kernel_launch(void* const* d_in, const int* in_sizes, int n_in,
                              void* d_out, int out_size, void* d_ws, size_t ws_size,
                              hipStream_t stream) {
    const float* x    = (const float*)d_in[0];
    const int*   ei   = (const int*)d_in[1];
    const int*   batch= (const int*)d_in[2];
    const float* W1a  = (const float*)d_in[3];
    const float* b1a  = (const float*)d_in[4];
    const float* W1b  = (const float*)d_in[5];
    const float* b1b  = (const float*)d_in[6];
    const float* W2a  = (const float*)d_in[7];
    const float* b2a  = (const float*)d_in[8];
    const float* W2b  = (const float*)d_in[9];
    const float* b2b  = (const float*)d_in[10];
    const float* Wfc  = (const float*)d_in[11];
    const float* bfc  = (const float*)d_in[12];

    const int N = in_sizes[0];
    const int E = in_sizes[1] / 2;
    const int G = out_size;
    const int NB = (N + 255) >> BSH;
    const int chunk = (E + NBLKA - 1) / NBLKA;
    const int B = 256;

    auto rnd4 = [](size_t v) { return (v + 3) & ~(size_t)3; };
    size_t o_cur  = 0;                                    // cursor/bucketCnt [1024] (zeroed)
    size_t o_dn   = 1024;                                 // doneCnt [1]            (zeroed)
    size_t o_sc   = 1025;                                 // sumsCnt [9G]           (zeroed)
    size_t zelems = o_sc + (size_t)9 * G;                 // ---- memset to here ----
    size_t o_ns   = rnd4(zelems);                         // nodeStart [NB*256+1]
    size_t o_h1   = rnd4(o_ns + ((size_t)NB << BSH) + 1); // h1 fp8 [2 words/node]
    size_t o_pk   = rnd4(o_h1 + ((size_t)NB << BSH) * 2); // packed [NB*BCAP]
    size_t total  = o_pk + (size_t)NB * BCAP;

    bool srcFits = (N <= (1 << 18));
    bool chunkFits = (chunk <= SCAP);
    bool capOK = ((size_t)E / NB) * 10 <= (size_t)BCAP * 9;
    if (NB <= 1024 && srcFits && chunkFits && capOK && ws_size >= total * 4) {
        int*      wsi = (int*)d_ws;
        float*    wsf = (float*)d_ws;
        unsigned* wsu = (unsigned*)d_ws;
        int*      cursor    = wsi + o_cur;
        unsigned* doneCnt   = wsu + o_dn;
        float*    sumsCnt   = wsf + o_sc;
        int*      nodeStart = wsi + o_ns;
        uint2*    h1        = (uint2*)(wsu + o_h1);
        unsigned* packed    = wsu + o_pk;

        hipMemsetAsync(d_ws, 0, zelems * 4, stream);
        scatterK<<<NBLKA, BTH, 0, stream>>>(ei, E, NB, chunk, cursor, packed);
        sortL1K<<<NB, TS, 0, stream>>>(packed, cursor, x, N, W1a, b1a, W1b, b1b,
                                       nodeStart, h1);
        layer2K<<<NB, 1024, 0, stream>>>(packed, nodeStart, cursor, h1, N,
                                         W2a, b2a, W2b, b2b, batch, sumsCnt,
                                         Wfc, bfc, (float*)d_out, G, doneCnt);
    } else {
        float* ws     = (float*)d_ws;
        float* agg1   = ws;
        float* agg2   = agg1 + (size_t)N;
        float* sums   = agg2 + (size_t)8 * N;
        float* counts = sums + (size_t)8 * G;
        float* h1     = counts + (size_t)G;
        hipMemsetAsync(ws, 0, ((size_t)9 * N + (size_t)9 * G) * sizeof(float), stream);
        edge_agg1<<<(E + B - 1) / B, B, 0, stream>>>(ei, x, agg1, E);
        node1F<<<(N + B - 1) / B, B, 0, stream>>>(x, agg1, W1a, b1a, W1b, b1b, h1, N);
        long long tot = (long long)E * H;
        edge_agg2<<<(int)((tot + B - 1) / B), B, 0, stream>>>(ei, h1, agg2, E);
        node2F<<<(N + B - 1) / B, B, 0, stream>>>(h1, agg2, W2a, b2a, W2b, b2b, batch,
                                                  sums, counts, N);
        finalF<<<(G + B - 1) / B, B, 0, stream>>>(sums, counts, Wfc, bfc, (float*)d_out, G);
    }
}

// Round 10
// 254.721 us; speedup vs baseline: 1.2132x; 1.1666x over previous
//
#include <hip/hip_runtime.h>
#include <hip/hip_fp8.h>
#include <math.h>

#define H 8
#define NBLKA 256          // #chunks for scatter pass
#define BTH 1024           // threads for scatter
#define BSH 8              // 256 nodes per bucket
#define BCAP 9216          // per-bucket slot capacity (mean 8184 + 11 sigma for E=6.4M)
#define TS 1024            // threads for fused sort+layer1 (4 lanes/node)
#define SCAP 25600         // LDS capacity for scatter chunk (100 KB)
#define POOLG 128          // max graphs spanned per block in pooling fast path

// ---- fp8 e4m3 helpers via HIP type (HW cvt on gfx950) ----
__device__ __forceinline__ unsigned f2fp8(float f) {
    __hip_fp8_e4m3 q(f);
    return (unsigned)q.__x;
}
__device__ __forceinline__ float fp8f(unsigned v) {
    __hip_fp8_e4m3 q;
    q.__x = (__hip_fp8_storage_t)v;
    return (float)q;
}
#if defined(__has_builtin)
#if __has_builtin(__builtin_amdgcn_cvt_pk_f32_fp8)
#define HAVE_CVT_PK_FP8 1
#endif
#endif
typedef float v2f __attribute__((ext_vector_type(2)));
// unpack 8 fp8 bytes -> 8 floats; packed HW cvt (1 instr / 2 elems) when available
__device__ __forceinline__ void unpack8(float* f, uint2 v) {
#ifdef HAVE_CVT_PK_FP8
    v2f f01 = __builtin_amdgcn_cvt_pk_f32_fp8((int)v.x, false);
    v2f f23 = __builtin_amdgcn_cvt_pk_f32_fp8((int)v.x, true);
    v2f f45 = __builtin_amdgcn_cvt_pk_f32_fp8((int)v.y, false);
    v2f f67 = __builtin_amdgcn_cvt_pk_f32_fp8((int)v.y, true);
    f[0] = f01.x; f[1] = f01.y; f[2] = f23.x; f[3] = f23.y;
    f[4] = f45.x; f[5] = f45.y; f[6] = f67.x; f[7] = f67.y;
#else
    f[0] = fp8f(v.x & 255u);         f[1] = fp8f((v.x >> 8) & 255u);
    f[2] = fp8f((v.x >> 16) & 255u); f[3] = fp8f(v.x >> 24);
    f[4] = fp8f(v.y & 255u);         f[5] = fp8f((v.y >> 8) & 255u);
    f[6] = fp8f((v.y >> 16) & 255u); f[7] = fp8f(v.y >> 24);
#endif
}
__device__ __forceinline__ void acc8(float* a, uint2 v) {
    float f[8];
    unpack8(f, v);
#pragma unroll
    for (int j = 0; j < 8; j++) a[j] += f[j];
}

// ====== Phase A: atomic-reservation scatter into fixed-capacity bucket regions ======
// NT policy: ei is a single-use stream per pass (cached pass-1 would thrash 4MB XCD-L2
// at 32 blocks x 200KB chunk) -- proven R0/R6 form, untouched.
__global__ __launch_bounds__(BTH) void scatterK(const int* __restrict__ ei, int E, int NB,
                                                int chunk, int* __restrict__ cursor,
                                                unsigned* __restrict__ packed) {
    __shared__ unsigned ss[SCAP];
    __shared__ int cnt[1024], sc[1024], base[1024], cur[1024];
    int t = threadIdx.x, blk = blockIdx.x;
    cnt[t] = 0;
    __syncthreads();
    int s = blk * chunk, e = min(E, s + chunk);
    // pass 1: count dst buckets (NT stream)
    for (int i = s + t; i < e; i += BTH)
        atomicAdd(&cnt[__builtin_nontemporal_load(ei + E + i) >> BSH], 1);
    __syncthreads();
    int c = cnt[t];
    sc[t] = c;
    __syncthreads();
    for (int off = 1; off < 1024; off <<= 1) {
        int v = (t >= off) ? sc[t - off] : 0;
        __syncthreads();
        sc[t] += v;
        __syncthreads();
    }
    cur[t] = sc[t] - c;                       // local exclusive start
    base[t] = (t < NB && c > 0) ? atomicAdd(&cursor[t], c) : 0;
    __syncthreads();
    // pass 2: re-read ei (L3-warm), LDS bucket-sort
    for (int i = s + t; i < e; i += BTH) {
        int src = __builtin_nontemporal_load(ei + i);
        int dst = __builtin_nontemporal_load(ei + E + i);
        int pos = atomicAdd(&cur[dst >> BSH], 1);
        ss[pos] = ((unsigned)src << 8) | (unsigned)(dst & 255);
    }
    __syncthreads();
    // copy-out: wave per bucket, lane per element -> coalesced full lines
    int wave = t >> 6, lane = t & 63;
    for (int j = wave; j < NB; j += (BTH >> 6)) {
        int n = cnt[j];
        int ls = sc[j] - n;
        int bs = base[j];
        int m = min(n, BCAP - bs);            // capacity guard (never hit for random dst)
        int gs = j * BCAP + bs;
        for (int k = lane; k < m; k += 64)
            packed[gs + k] = ss[ls + k];
    }
}

// ====== Phase B fused: counting sort with pass-1 register-carried x-gather + layer-1 MLP ======
// pass 1 loads each packed word to count; at that moment src is known -> issue x[src]
// immediately, keep pk[9]/xr[9] in registers (static unroll, no scratch). 9-deep gather
// overlaps the counting atomics + prefix scan. pass 2 scatters the VALUE into sv[pos];
// segmented sum reads LDS. Cached x (reused ~32x; NT/sc0 both tested worse-or-equal).
// No launch bounds (R1's VGPR cap regressed). LDS ss+sv+counters ~78KB -> 2 blocks/CU.
__global__ void sortL1K(unsigned* __restrict__ packed, const int* __restrict__ bucketCnt,
                        const float* __restrict__ x, int N,
                        const float* __restrict__ W1a, const float* __restrict__ b1a,
                        const float* __restrict__ W1b, const float* __restrict__ b1b,
                        int* __restrict__ nodeStart, uint2* __restrict__ h1) {
    __shared__ unsigned ss[BCAP];             // sorted srcs (written back for layer2K)
    __shared__ float sv[BCAP];                // x[src] aligned with ss
    __shared__ int cnt[256], sb[256], cur[256];
    __shared__ float sW1a[H], sb1a[H], sW1b[H * H], sb1b[H];
    int t = threadIdx.x, b = blockIdx.x;
    if (t < 256) cnt[t] = 0;
    else if (t < 256 + H) { int j = t - 256; sW1a[j] = W1a[j]; sb1a[j] = b1a[j]; sb1b[j] = b1b[j]; }
    else if (t < 256 + H + H * H) { int j = t - 256 - H; sW1b[j] = W1b[j]; }
    __syncthreads();
    int s = b * BCAP;
    int n_e = min(bucketCnt[b], BCAP);
    // pass 1: count exact dst + early x-gather into registers (9 slots cover BCAP)
    unsigned pk[9];
    float xr[9];
#pragma unroll
    for (int k = 0; k < 9; k++) {
        int i = t + (k << 10);
        if (i < n_e) {
            unsigned p = packed[s + i];       // cached: packed is L2-warm from scatterK
            pk[k] = p;
            xr[k] = x[p >> 8];                // issued here; consumed in pass 2
            atomicAdd(&cnt[p & 255u], 1);
        }
    }
    __syncthreads();
    if (t < 256) sb[t] = cnt[t];
    __syncthreads();
    for (int off = 1; off < 256; off <<= 1) {
        int add = (t < 256 && t >= off) ? sb[t - off] : 0;
        __syncthreads();
        if (t < 256) sb[t] += add;
        __syncthreads();
    }
    if (t < 256) {
        int excl = sb[t] - cnt[t];
        cur[t] = excl;
        nodeStart[(b << BSH) + t] = s + excl;
    }
    __syncthreads();
    // pass 2: scatter src + value from registers into exact-dst order
#pragma unroll
    for (int k = 0; k < 9; k++) {
        int i = t + (k << 10);
        if (i < n_e) {
            unsigned p = pk[k];
            int pos = atomicAdd(&cur[p & 255u], 1);
            ss[pos] = p >> 8;
            sv[pos] = xr[k];
        }
    }
    __syncthreads();
    // write back sorted srcs for layer2K
    for (int i = t; i < n_e; i += TS) packed[s + i] = ss[i];
    // layer-1: 4 lanes/node; segmented sum straight from LDS values
    int node = t >> 2, q4 = t & 3;
    int gn = (b << BSH) + node;
    float xself = x[min(gn, N - 1)];          // hoisted: overlaps LDS sum
    int lo = sb[node] - cnt[node], hi = sb[node];
    float sum = 0.f;
    for (int k = lo + q4; k < hi; k += 4) sum += sv[k];
    sum += __shfl_xor(sum, 1, 64);
    sum += __shfl_xor(sum, 2, 64);
    if (q4 == 0 && gn < N) {
        float z = xself + sum;
        float tv[H];
#pragma unroll
        for (int k = 0; k < H; k++) tv[k] = fmaxf(fmaf(z, sW1a[k], sb1a[k]), 0.f);
        float hv[H];
#pragma unroll
        for (int j = 0; j < H; j++) {
            float a = sb1b[j];
#pragma unroll
            for (int k = 0; k < H; k++) a += tv[k] * sW1b[k * H + j];
            hv[j] = a > 0.f ? a : (expf(a) - 1.f);   // elu
        }
        uint2 o;
        o.x = f2fp8(hv[0]) | (f2fp8(hv[1]) << 8) | (f2fp8(hv[2]) << 16) | (f2fp8(hv[3]) << 24);
        o.y = f2fp8(hv[4]) | (f2fp8(hv[5]) << 8) | (f2fp8(hv[6]) << 16) | (f2fp8(hv[7]) << 24);
        h1[gn] = o;
    }
}

// ====== Phase C: layer-2, LDS-staged index list + unroll-x8 CACHED gather (h1 L2-resident) ======
// __launch_bounds__(1024, 8): cap VGPR at 64 so 2 blocks (32 waves) stay resident.
// NO device-scope fences/atomics in here (R9: one per block cost +45us via L2 invalidation).
__global__ __launch_bounds__(1024, 8) void layer2K(
        const unsigned* __restrict__ packed, const int* __restrict__ nodeStart,
        const int* __restrict__ bucketCnt, const uint2* __restrict__ h1, int N,
        const float* __restrict__ W2a, const float* __restrict__ b2a,
        const float* __restrict__ W2b, const float* __restrict__ b2b,
        const int* __restrict__ batch, float* __restrict__ sumsCnt) {
    __shared__ unsigned ss[BCAP];
    __shared__ int sNS[257];
    __shared__ float pool[POOLG * 9];
    __shared__ float sW2a[H * H], sb2a[H], sW2b[H * H], sb2b[H];
    int t = threadIdx.x, b = blockIdx.x;
    int s = b * BCAP;
    int n_e = min(bucketCnt[b], BCAP);
    // stage sorted index list (coalesced, NT: single-use stream, don't evict h1 from L2)
    for (int i = t; i < n_e; i += 1024)
        ss[i] = __builtin_nontemporal_load(packed + s + i);
    if (t < 256) sNS[t] = nodeStart[(b << BSH) + t] - s;
    if (t == 256) sNS[256] = 0;               // patched below
    if (t < H) { sb2a[t] = b2a[t]; sb2b[t] = b2b[t]; }
    else if (t >= 64 && t < 64 + H * H) sW2a[t - 64] = W2a[t - 64];
    else if (t >= 192 && t < 192 + H * H) sW2b[t - 192] = W2b[t - 192];
    __syncthreads();
    if (t == 0) sNS[256] = n_e;
    __syncthreads();
    int node = t >> 2, q4 = t & 3;
    int gn = (b << BSH) + node;
    uint2 vself = h1[gn];                     // hoisted (h1 region spans all gn); overlaps loop
    int lo = sNS[node], hi = sNS[node + 1];
    float a[H] = {0.f, 0.f, 0.f, 0.f, 0.f, 0.f, 0.f, 0.f};
    for (int k0 = lo + q4; k0 < hi; k0 += 32) {
        unsigned i0 = ss[k0];
        unsigned i1 = ss[min(k0 + 4,  hi - 1)];
        unsigned i2 = ss[min(k0 + 8,  hi - 1)];
        unsigned i3 = ss[min(k0 + 12, hi - 1)];
        unsigned i4 = ss[min(k0 + 16, hi - 1)];
        unsigned i5 = ss[min(k0 + 20, hi - 1)];
        unsigned i6 = ss[min(k0 + 24, hi - 1)];
        unsigned i7 = ss[min(k0 + 28, hi - 1)];
        uint2 v0 = h1[i0];                    // 8 independent CACHED loads -> 8 outstanding
        uint2 v1 = h1[i1];
        uint2 v2 = h1[i2];
        uint2 v3 = h1[i3];
        uint2 v4 = h1[i4];
        uint2 v5 = h1[i5];
        uint2 v6 = h1[i6];
        uint2 v7 = h1[i7];
        acc8(a, v0);
        if (k0 + 4  < hi) acc8(a, v1);
        if (k0 + 8  < hi) acc8(a, v2);
        if (k0 + 12 < hi) acc8(a, v3);
        if (k0 + 16 < hi) acc8(a, v4);
        if (k0 + 20 < hi) acc8(a, v5);
        if (k0 + 24 < hi) acc8(a, v6);
        if (k0 + 28 < hi) acc8(a, v7);
    }
#pragma unroll
    for (int j = 0; j < H; j++) {
        a[j] += __shfl_xor(a[j], 1, 64);
        a[j] += __shfl_xor(a[j], 2, 64);
    }
    bool valid = (q4 == 0) && (gn < N);
    float h2[H];
    int g = 0;
    if (valid) {
        float zs[H];
        unpack8(zs, vself);
        float z[H];
#pragma unroll
        for (int j = 0; j < H; j++) z[j] = zs[j] + a[j];
        float tv[H];
#pragma unroll
        for (int k = 0; k < H; k++) {
            float acc = sb2a[k];
#pragma unroll
            for (int j = 0; j < H; j++) acc += z[j] * sW2a[j * H + k];
            tv[k] = fmaxf(acc, 0.f);
        }
#pragma unroll
        for (int j = 0; j < H; j++) {
            float acc = sb2b[j];
#pragma unroll
            for (int k = 0; k < H; k++) acc += tv[k] * sW2b[k * H + j];
            h2[j] = acc;
        }
        g = batch[gn];
    }
    int gfirst = batch[min(b << BSH, N - 1)];
    int glast  = batch[min((b << BSH) + 255, N - 1)];
    int span = glast - gfirst + 1;
    if (span <= POOLG) {
        int span9 = span * 9;
        for (int j = t; j < span9; j += 1024) pool[j] = 0.f;
        __syncthreads();
        if (valid) {
            float* p = &pool[(g - gfirst) * 9];
#pragma unroll
            for (int j = 0; j < H; j++) atomicAdd(p + j, h2[j]);
            atomicAdd(p + 8, 1.f);
        }
        __syncthreads();
        for (int j = t; j < span9; j += 1024)
            atomicAdd(&sumsCnt[(size_t)gfirst * 9 + j], pool[j]);
    } else if (valid) {
        float* p = &sumsCnt[(size_t)g * 9];
#pragma unroll
        for (int j = 0; j < H; j++) atomicAdd(p + j, h2[j]);
        atomicAdd(p + 8, 1.f);
    }
}

__global__ void finalK(const float* __restrict__ sumsCnt, const float* __restrict__ Wfc,
                       const float* __restrict__ bfc, float* __restrict__ out, int G) {
    int g = blockIdx.x * blockDim.x + threadIdx.x;
    if (g >= G) return;
    const float* s = &sumsCnt[(size_t)g * 9];
    float c = fmaxf(s[8], 1.f);
    float dot = 0.f;
#pragma unroll
    for (int j = 0; j < H; j++) dot += s[j] * Wfc[j];
    float a = dot / c + bfc[0];
    out[g] = 1.f / (1.f + expf(-a));
}

// ============================ FALLBACK (R1 atomic path) ============================
__global__ void edge_agg1(const int* __restrict__ ei, const float* __restrict__ x,
                          float* __restrict__ agg1, int E) {
    int e = blockIdx.x * blockDim.x + threadIdx.x;
    if (e >= E) return;
    atomicAdd(&agg1[ei[E + e]], x[ei[e]]);
}
__global__ void node1F(const float* __restrict__ x, const float* __restrict__ agg1,
                       const float* __restrict__ W1a, const float* __restrict__ b1a,
                       const float* __restrict__ W1b, const float* __restrict__ b1b,
                       float* __restrict__ h1, int N) {
    int n = blockIdx.x * blockDim.x + threadIdx.x;
    if (n >= N) return;
    float z = x[n] + agg1[n];
    float tv[H];
#pragma unroll
    for (int k = 0; k < H; k++) tv[k] = fmaxf(z * W1a[k] + b1a[k], 0.f);
#pragma unroll
    for (int j = 0; j < H; j++) {
        float acc = b1b[j];
#pragma unroll
        for (int k = 0; k < H; k++) acc += tv[k] * W1b[k * H + j];
        h1[(size_t)n * H + j] = acc > 0.f ? acc : (expf(acc) - 1.f);
    }
}
__global__ void edge_agg2(const int* __restrict__ ei, const float* __restrict__ h1,
                          float* __restrict__ agg2, int E) {
    long long i = (long long)blockIdx.x * blockDim.x + threadIdx.x;
    if (i >= (long long)E * H) return;
    int e = (int)(i >> 3), k = (int)(i & 7);
    atomicAdd(&agg2[(size_t)ei[E + e] * H + k], h1[(size_t)ei[e] * H + k]);
}
__global__ void node2F(const float* __restrict__ h1, const float* __restrict__ agg2,
                       const float* __restrict__ W2a, const float* __restrict__ b2a,
                       const float* __restrict__ W2b, const float* __restrict__ b2b,
                       const int* __restrict__ batch,
                       float* __restrict__ sums, float* __restrict__ counts, int N) {
    int n = blockIdx.x * blockDim.x + threadIdx.x;
    if (n >= N) return;
    float z[H], tv[H];
#pragma unroll
    for (int j = 0; j < H; j++) z[j] = h1[(size_t)n * H + j] + agg2[(size_t)n * H + j];
#pragma unroll
    for (int k = 0; k < H; k++) {
        float a = b2a[k];
#pragma unroll
        for (int j = 0; j < H; j++) a += z[j] * W2a[j * H + k];
        tv[k] = fmaxf(a, 0.f);
    }
    int g = batch[n];
#pragma unroll
    for (int j = 0; j < H; j++) {
        float a = b2b[j];
#pragma unroll
        for (int k = 0; k < H; k++) a += tv[k] * W2b[k * H + j];
        atomicAdd(&sums[(size_t)g * H + j], a);
    }
    atomicAdd(&counts[g], 1.f);
}
__global__ void finalF(const float* __restrict__ sums, const float* __restrict__ counts,
                       const float* __restrict__ Wfc, const float* __restrict__ bfc,
                       float* __restrict__ out, int G) {
    int g = blockIdx.x * blockDim.x + threadIdx.x;
    if (g >= G) return;
    float c = fmaxf(counts[g], 1.f);
    float acc = bfc[0];
#pragma unroll
    for (int j = 0; j < H; j++) acc += (sums[(size_t)g * H + j] / c) * Wfc[j];
    out[g] = 1.f / (1.f + expf(-acc));
}

// ============================ LAUNCH ============================
extern "C" void kernel_launch(void* const* d_in, const int* in_sizes, int n_in,
                              void* d_out, int out_size, void* d_ws, size_t ws_size,
                              hipStream_t stream) {
    const float* x    = (const float*)d_in[0];
    const int*   ei   = (const int*)d_in[1];
    const int*   batch= (const int*)d_in[2];
    const float* W1a  = (const float*)d_in[3];
    const float* b1a  = (const float*)d_in[4];
    const float* W1b  = (const float*)d_in[5];
    const float* b1b  = (const float*)d_in[6];
    const float* W2a  = (const float*)d_in[7];
    const float* b2a  = (const float*)d_in[8];
    const float* W2b  = (const float*)d_in[9];
    const float* b2b  = (const float*)d_in[10];
    const float* Wfc  = (const float*)d_in[11];
    const float* bfc  = (const float*)d_in[12];

    const int N = in_sizes[0];
    const int E = in_sizes[1] / 2;
    const int G = out_size;
    const int NB = (N + 255) >> BSH;
    const int chunk = (E + NBLKA - 1) / NBLKA;
    const int B = 256;

    auto rnd4 = [](size_t v) { return (v + 3) & ~(size_t)3; };
    size_t o_cur  = 0;                                    // cursor/bucketCnt [1024] (zeroed)
    size_t o_sc   = 1024;                                 // sumsCnt [9G]           (zeroed)
    size_t zelems = o_sc + (size_t)9 * G;                 // ---- memset to here ----
    size_t o_ns   = rnd4(zelems);                         // nodeStart [NB*256+1]
    size_t o_h1   = rnd4(o_ns + ((size_t)NB << BSH) + 1); // h1 fp8 [2 words/node]
    size_t o_pk   = rnd4(o_h1 + ((size_t)NB << BSH) * 2); // packed [NB*BCAP]
    size_t total  = o_pk + (size_t)NB * BCAP;

    bool srcFits = (N <= (1 << 18));
    bool chunkFits = (chunk <= SCAP);
    bool capOK = ((size_t)E / NB) * 10 <= (size_t)BCAP * 9;
    if (NB <= 1024 && srcFits && chunkFits && capOK && ws_size >= total * 4) {
        int*      wsi = (int*)d_ws;
        float*    wsf = (float*)d_ws;
        unsigned* wsu = (unsigned*)d_ws;
        int*      cursor    = wsi + o_cur;
        float*    sumsCnt   = wsf + o_sc;
        int*      nodeStart = wsi + o_ns;
        uint2*    h1        = (uint2*)(wsu + o_h1);
        unsigned* packed    = wsu + o_pk;

        hipMemsetAsync(d_ws, 0, zelems * 4, stream);
        scatterK<<<NBLKA, BTH, 0, stream>>>(ei, E, NB, chunk, cursor, packed);
        sortL1K<<<NB, TS, 0, stream>>>(packed, cursor, x, N, W1a, b1a, W1b, b1b,
                                       nodeStart, h1);
        layer2K<<<NB, 1024, 0, stream>>>(packed, nodeStart, cursor, h1, N,
                                         W2a, b2a, W2b, b2b, batch, sumsCnt);
        finalK<<<(G + B - 1) / B, B, 0, stream>>>(sumsCnt, Wfc, bfc, (float*)d_out, G);
    } else {
        float* ws     = (float*)d_ws;
        float* agg1   = ws;
        float* agg2   = agg1 + (size_t)N;
        float* sums   = agg2 + (size_t)8 * N;
        float* counts = sums + (size_t)8 * G;
        float* h1     = counts + (size_t)G;
        hipMemsetAsync(ws, 0, ((size_t)9 * N + (size_t)9 * G) * sizeof(float), stream);
        edge_agg1<<<(E + B - 1) / B, B, 0, stream>>>(ei, x, agg1, E);
        node1F<<<(N + B - 1) / B, B, 0, stream>>>(x, agg1, W1a, b1a, W1b, b1b, h1, N);
        long long tot = (long long)E * H;
        edge_agg2<<<(int)((tot + B - 1) / B), B, 0, stream>>>(ei, h1, agg2, E);
        node2F<<<(N + B - 1) / B, B, 0, stream>>>(h1, agg2, W2a, b2a, W2b, b2b, batch,
                                                  sums, counts, N);
        finalF<<<(G + B - 1) / B, B, 0, stream>>>(sums, counts, Wfc, bfc, (float*)d_out, G);
    }
}